// Round 3
// baseline (360.617 us; speedup 1.0000x reference)
//
#include <hip/hip_runtime.h>
#include <hip/hip_cooperative_groups.h>

namespace cg = cooperative_groups;

// Problem: SpatialTransform
//   x:     (16, 256, 256, 32) f32
//   W_loc: (32, 6) f32
//   b_loc: (6) f32
//   out:   (16, 256, 256, 32) f32
//
// out = bilinear_sample(x, affine_grid(theta)), theta = mean_pool(x) @ W_loc + b_loc
// Single cooperative kernel: sum -> grid.sync -> theta -> grid.sync -> gather.

#define NIMG 16
#define HDIM 256
#define WDIM 256
#define CH   32
#define HW   (HDIM * WDIM)
#define NBLK 1024
#define CPI  64     // phase-1 chunks per image (NBLK / NIMG)

typedef float f32x4 __attribute__((ext_vector_type(4)));

__global__ __launch_bounds__(256) void st_fused(
    const float* __restrict__ x, const float* __restrict__ W_loc,
    const float* __restrict__ b_loc, float* __restrict__ partials,
    float* __restrict__ theta_ws, float* __restrict__ out) {
    const int bid = (int)blockIdx.x;
    const int tid = (int)threadIdx.x;
    const int cgp = tid & 7;    // float4 channel group 0..7
    const int sp  = tid >> 3;   // spatial slot 0..31

    __shared__ float4 red[256];
    __shared__ float  thr_red[8][CH];
    __shared__ float  mean_s[CH];

    cg::grid_group grid = cg::this_grid();

    // ---- phase 1: partial channel sums.  block = (image n, chunk blk) ----
    {
        const int n = bid >> 6, blk = bid & (CPI - 1);
        const float4* xp = (const float4*)(x + (size_t)n * HW * CH);
        float4 acc = make_float4(0.f, 0.f, 0.f, 0.f);
        for (int s = blk * 32 + sp; s < HW; s += CPI * 32) {
            float4 v = xp[(size_t)s * 8 + cgp];
            acc.x += v.x; acc.y += v.y; acc.z += v.z; acc.w += v.w;
        }
        red[tid] = acc;
        __syncthreads();
        for (int st = 16; st >= 1; st >>= 1) {
            if (sp < st) {
                float4 o = red[(sp + st) * 8 + cgp];
                acc.x += o.x; acc.y += o.y; acc.z += o.z; acc.w += o.w;
                red[tid] = acc;
            }
            __syncthreads();
        }
        if (sp == 0) {
            // partials layout: [n][blk][CH]
            ((float4*)(partials + ((size_t)(n * CPI + blk)) * CH))[cgp] = acc;
        }
    }

    __threadfence();
    grid.sync();

    // ---- theta: blocks 0..15 in parallel, block n handles image n ----
    if (bid < NIMG) {
        const int c = tid & 31, k8 = tid >> 5;  // k8 = 0..7
        float s = 0.f;
        for (int j = 0; j < 8; ++j)
            s += partials[(size_t)(bid * CPI + k8 * 8 + j) * CH + c];
        thr_red[k8][c] = s;
        __syncthreads();
        if (k8 == 0) {
            float m = 0.f;
            for (int j = 0; j < 8; ++j) m += thr_red[j][c];
            mean_s[c] = m * (1.0f / (float)HW);
        }
        __syncthreads();
        if (tid < 6) {
            float acc = b_loc[tid];
            for (int c2 = 0; c2 < CH; ++c2)
                acc = fmaf(mean_s[c2], W_loc[c2 * 6 + tid], acc);
            theta_ws[bid * 6 + tid] = acc;
        }
    }

    __threadfence();
    grid.sync();

    // ---- phase 2: bilinear gather, 32 4x8-pixel tiles per block ----
    // XCD-contiguous: each XCD (bid&7) owns 4096 consecutive tiles (2 images).
    const int xcd  = bid & 7, sub = bid >> 3;     // sub = 0..127
    const int tile_base = xcd * 4096 + sub * 32;  // never crosses an image
    const int n2 = tile_base >> 11;               // 2048 tiles per image
    const float* th = theta_ws + n2 * 6;
    const float t00 = th[0], t01 = th[1], t02 = th[2];
    const float t10 = th[3], t11 = th[4], t12 = th[5];
    const float4* xp = (const float4*)(x + (size_t)n2 * HW * CH);
    f32x4* op = (f32x4*)(out + (size_t)n2 * HW * CH);
    const int p = tid >> 3;                       // pixel in tile 0..31

    for (int it = 0; it < 32; ++it) {
        const int tl = (tile_base + it) & 2047;   // tile index within image
        const int ty = tl >> 5, tx = tl & 31;
        const int ho = ty * 4 + (p >> 3);
        const int wo = tx * 8 + (p & 7);

        const float gy = fmaf((float)ho, 2.0f / 255.0f, -1.0f);
        const float gx = fmaf((float)wo, 2.0f / 255.0f, -1.0f);

        const float uy = (fmaf(t00, gy, fmaf(t01, gx, t02)) + 1.0f) * 127.5f;
        const float ux = (fmaf(t10, gy, fmaf(t11, gx, t12)) + 1.0f) * 127.5f;

        const float fy = floorf(uy), fx = floorf(ux);
        const float ry = uy - fy, rx = ux - fx;
        const int iy = (int)fy, ix = (int)fx;
        const int iy0 = min(max(iy,     0), HDIM - 1);
        const int iy1 = min(max(iy + 1, 0), HDIM - 1);
        const int ix0 = min(max(ix,     0), WDIM - 1);
        const int ix1 = min(max(ix + 1, 0), WDIM - 1);

        float4 v00 = xp[(size_t)(iy0 * WDIM + ix0) * 8 + cgp];
        float4 v01 = xp[(size_t)(iy0 * WDIM + ix1) * 8 + cgp];
        float4 v10 = xp[(size_t)(iy1 * WDIM + ix0) * 8 + cgp];
        float4 v11 = xp[(size_t)(iy1 * WDIM + ix1) * 8 + cgp];

        const float w00 = (1.0f - ry) * (1.0f - rx);
        const float w01 = (1.0f - ry) * rx;
        const float w10 = ry * (1.0f - rx);
        const float w11 = ry * rx;

        f32x4 o;
        o.x = v00.x * w00 + v01.x * w01 + v10.x * w10 + v11.x * w11;
        o.y = v00.y * w00 + v01.y * w01 + v10.y * w10 + v11.y * w11;
        o.z = v00.z * w00 + v01.z * w01 + v10.z * w10 + v11.z * w11;
        o.w = v00.w * w00 + v01.w * w01 + v10.w * w10 + v11.w * w11;

        __builtin_nontemporal_store(o, &op[(size_t)(ho * WDIM + wo) * 8 + cgp]);
    }
}

extern "C" void kernel_launch(void* const* d_in, const int* in_sizes, int n_in,
                              void* d_out, int out_size, void* d_ws, size_t ws_size,
                              hipStream_t stream) {
    const float* x     = (const float*)d_in[0];
    const float* W_loc = (const float*)d_in[1];
    const float* b_loc = (const float*)d_in[2];
    float* out = (float*)d_out;

    // workspace layout: partials[NIMG*CPI*CH] f32, theta[16*6] f32
    float* partials = (float*)d_ws;
    float* theta    = partials + NIMG * CPI * CH;

    void* args[] = {(void*)&x, (void*)&W_loc, (void*)&b_loc,
                    (void*)&partials, (void*)&theta, (void*)&out};
    hipLaunchCooperativeKernel(reinterpret_cast<void*>(st_fused),
                               dim3(NBLK), dim3(256), args, 0, stream);
}

// Round 4
// 68.658 us; speedup vs baseline: 5.2523x; 5.2523x over previous
//
#include <hip/hip_runtime.h>

// Problem: SpatialTransform
//   x:     (16, 256, 256, 32) f32
//   W_loc: (32, 6) f32
//   b_loc: (6) f32
//   out:   (16, 256, 256, 32) f32
//
// out = bilinear_sample(x, affine_grid(theta)), theta = mean_pool(x) @ W_loc + b_loc
//
// R3 lesson: cooperative fusion (1024-block cap + grid.sync across 8 XCDs +
// VGPR=32 killing MLP) regressed 5x. Split kernels, maximize loads-in-flight.

#define NIMG 16
#define HDIM 256
#define WDIM 256
#define CH   32
#define HW   (HDIM * WDIM)
#define BPI  128   // sum-kernel blocks per image

typedef float f32x4 __attribute__((ext_vector_type(4)));

// ---------------------------------------------------------------------------
// Kernel 1: per-(n,c) partial sums. 2048 blocks, 2 independent acc chains.
// partials layout: [BPI][NIMG][CH]
// ---------------------------------------------------------------------------
__global__ __launch_bounds__(256) void st_sum_kernel(
    const float* __restrict__ x, float* __restrict__ partials) {
    const int n   = blockIdx.x >> 7;
    const int blk = blockIdx.x & (BPI - 1);
    const int tid = threadIdx.x;
    const int cg  = tid & 7;    // float4 channel group
    const int sp  = tid >> 3;   // spatial slot 0..31

    const float4* xp = (const float4*)(x + (size_t)n * HW * CH);
    float4 a0 = make_float4(0.f, 0.f, 0.f, 0.f);
    float4 a1 = make_float4(0.f, 0.f, 0.f, 0.f);
    // 16 spatial iterations total, unrolled 2x as independent chains
    int s = blk * 32 + sp;
    #pragma unroll
    for (int it = 0; it < 8; ++it) {
        float4 v0 = xp[(size_t)s * 8 + cg];
        float4 v1 = xp[(size_t)(s + BPI * 32) * 8 + cg];
        a0.x += v0.x; a0.y += v0.y; a0.z += v0.z; a0.w += v0.w;
        a1.x += v1.x; a1.y += v1.y; a1.z += v1.z; a1.w += v1.w;
        s += BPI * 64;
    }
    a0.x += a1.x; a0.y += a1.y; a0.z += a1.z; a0.w += a1.w;

    __shared__ float4 red[256];
    red[tid] = a0;
    __syncthreads();
    for (int stride = 16; stride >= 1; stride >>= 1) {
        if (sp < stride) {
            float4 o = red[(sp + stride) * 8 + cg];
            a0.x += o.x; a0.y += o.y; a0.z += o.z; a0.w += o.w;
            red[tid] = a0;
        }
        __syncthreads();
    }
    if (sp == 0) {
        ((float4*)(partials + ((size_t)blk * NIMG + n) * CH))[cg] = a0;
    }
}

// ---------------------------------------------------------------------------
// Kernel 2: reduce partials -> means -> theta. 512 threads, one per (n,c).
// ---------------------------------------------------------------------------
__global__ __launch_bounds__(512) void st_theta_kernel(
    const float* __restrict__ partials, const float* __restrict__ W_loc,
    const float* __restrict__ b_loc, float* __restrict__ theta) {
    __shared__ float mean[NIMG * CH];
    const int t = threadIdx.x;  // n*32+c
    float s = 0.f;
    for (int b = 0; b < BPI; ++b) s += partials[b * NIMG * CH + t];
    mean[t] = s * (1.0f / (float)HW);
    __syncthreads();
    if (t < NIMG * 6) {
        const int n = t / 6, k = t % 6;
        float acc = b_loc[k];
        for (int c = 0; c < CH; ++c)
            acc = fmaf(mean[n * CH + c], W_loc[c * 6 + k], acc);
        theta[t] = acc;
    }
}

// ---------------------------------------------------------------------------
// Kernel 3: bilinear gather. One block = 4x16 pixel tile, 2 px per thread,
// 8 corner loads issued before consumption (MLP=8). 16384 blocks; XCD swizzle
// gives each XCD 2048 consecutive blocks = exactly 2 whole images.
// ---------------------------------------------------------------------------
__global__ __launch_bounds__(256) void st_interp_kernel(
    const float* __restrict__ x, const float* __restrict__ theta,
    float* __restrict__ out) {
    const int bid = (int)blockIdx.x;
    const int swz = (bid & 7) * 2048 + (bid >> 3);  // 8 XCDs contiguous
    const int n   = swz >> 10;                      // 1024 blocks per image
    const int r   = swz & 1023;
    const int ty  = r >> 4;                         // 64 tile-rows (4 px)
    const int tx  = r & 15;                         // 16 tile-cols (16 px)
    const int tid = threadIdx.x;
    const int p   = tid >> 3;                       // pixel slot 0..31
    const int cg  = tid & 7;                        // float4 channel group

    const int ho  = ty * 4 + (p >> 3);
    const int wo0 = tx * 16 + (p & 7);
    const int wo1 = wo0 + 8;

    const float* th = theta + n * 6;
    const float t00 = th[0], t01 = th[1], t02 = th[2];
    const float t10 = th[3], t11 = th[4], t12 = th[5];

    const float gy = fmaf((float)ho, 2.0f / 255.0f, -1.0f);
    const float gx0 = fmaf((float)wo0, 2.0f / 255.0f, -1.0f);
    const float gx1 = fmaf((float)wo1, 2.0f / 255.0f, -1.0f);

    const float uyA = (fmaf(t00, gy, fmaf(t01, gx0, t02)) + 1.0f) * 127.5f;
    const float uxA = (fmaf(t10, gy, fmaf(t11, gx0, t12)) + 1.0f) * 127.5f;
    const float uyB = (fmaf(t00, gy, fmaf(t01, gx1, t02)) + 1.0f) * 127.5f;
    const float uxB = (fmaf(t10, gy, fmaf(t11, gx1, t12)) + 1.0f) * 127.5f;

    const float fyA = floorf(uyA), fxA = floorf(uxA);
    const float fyB = floorf(uyB), fxB = floorf(uxB);
    const float ryA = uyA - fyA, rxA = uxA - fxA;
    const float ryB = uyB - fyB, rxB = uxB - fxB;

    const int iyA0 = min(max((int)fyA,     0), HDIM - 1);
    const int iyA1 = min(max((int)fyA + 1, 0), HDIM - 1);
    const int ixA0 = min(max((int)fxA,     0), WDIM - 1);
    const int ixA1 = min(max((int)fxA + 1, 0), WDIM - 1);
    const int iyB0 = min(max((int)fyB,     0), HDIM - 1);
    const int iyB1 = min(max((int)fyB + 1, 0), HDIM - 1);
    const int ixB0 = min(max((int)fxB,     0), WDIM - 1);
    const int ixB1 = min(max((int)fxB + 1, 0), WDIM - 1);

    const float4* xp = (const float4*)(x + (size_t)n * HW * CH);
    // issue all 8 loads before any consumption
    float4 a00 = xp[(size_t)(iyA0 * WDIM + ixA0) * 8 + cg];
    float4 a01 = xp[(size_t)(iyA0 * WDIM + ixA1) * 8 + cg];
    float4 a10 = xp[(size_t)(iyA1 * WDIM + ixA0) * 8 + cg];
    float4 a11 = xp[(size_t)(iyA1 * WDIM + ixA1) * 8 + cg];
    float4 b00 = xp[(size_t)(iyB0 * WDIM + ixB0) * 8 + cg];
    float4 b01 = xp[(size_t)(iyB0 * WDIM + ixB1) * 8 + cg];
    float4 b10 = xp[(size_t)(iyB1 * WDIM + ixB0) * 8 + cg];
    float4 b11 = xp[(size_t)(iyB1 * WDIM + ixB1) * 8 + cg];

    const float wA00 = (1.0f - ryA) * (1.0f - rxA);
    const float wA01 = (1.0f - ryA) * rxA;
    const float wA10 = ryA * (1.0f - rxA);
    const float wA11 = ryA * rxA;
    const float wB00 = (1.0f - ryB) * (1.0f - rxB);
    const float wB01 = (1.0f - ryB) * rxB;
    const float wB10 = ryB * (1.0f - rxB);
    const float wB11 = ryB * rxB;

    f32x4 oA, oB;
    oA.x = a00.x * wA00 + a01.x * wA01 + a10.x * wA10 + a11.x * wA11;
    oA.y = a00.y * wA00 + a01.y * wA01 + a10.y * wA10 + a11.y * wA11;
    oA.z = a00.z * wA00 + a01.z * wA01 + a10.z * wA10 + a11.z * wA11;
    oA.w = a00.w * wA00 + a01.w * wA01 + a10.w * wA10 + a11.w * wA11;
    oB.x = b00.x * wB00 + b01.x * wB01 + b10.x * wB10 + b11.x * wB11;
    oB.y = b00.y * wB00 + b01.y * wB01 + b10.y * wB10 + b11.y * wB11;
    oB.z = b00.z * wB00 + b01.z * wB01 + b10.z * wB10 + b11.z * wB11;
    oB.w = b00.w * wB00 + b01.w * wB01 + b10.w * wB10 + b11.w * wB11;

    f32x4* op = (f32x4*)(out + (size_t)n * HW * CH);
    __builtin_nontemporal_store(oA, &op[(size_t)(ho * WDIM + wo0) * 8 + cg]);
    __builtin_nontemporal_store(oB, &op[(size_t)(ho * WDIM + wo1) * 8 + cg]);
}

extern "C" void kernel_launch(void* const* d_in, const int* in_sizes, int n_in,
                              void* d_out, int out_size, void* d_ws, size_t ws_size,
                              hipStream_t stream) {
    const float* x     = (const float*)d_in[0];
    const float* W_loc = (const float*)d_in[1];
    const float* b_loc = (const float*)d_in[2];
    float* out = (float*)d_out;

    // workspace layout: partials[BPI*NIMG*CH] f32, theta[16*6] f32
    float* partials = (float*)d_ws;
    float* theta    = partials + BPI * NIMG * CH;

    st_sum_kernel<<<NIMG * BPI, 256, 0, stream>>>(x, partials);
    st_theta_kernel<<<1, 512, 0, stream>>>(partials, W_loc, b_loc, theta);
    st_interp_kernel<<<NIMG * (HW / 64), 256, 0, stream>>>(x, theta, out);
}

// Round 5
// 65.031 us; speedup vs baseline: 5.5453x; 1.0558x over previous
//
#include <hip/hip_runtime.h>

// Problem: SpatialTransform
//   x:     (16, 256, 256, 32) f32
//   W_loc: (32, 6) f32
//   b_loc: (6) f32
//   out:   (16, 256, 256, 32) f32
//
// out = bilinear_sample(x, affine_grid(theta)), theta = mean_pool(x) @ W_loc + b_loc
//
// Structure (R5): two kernels.
//   k1: per-(n,c) partial sums -> partials[BPI][NIMG][CH]
//   k2: each block recomputes theta from partials (8KB L2-hot, bitwise
//       identical across blocks of an image), then bilinear-gathers its tile.
// R3 lesson: cooperative fusion regressed 5x (1024-block cap, grid.sync cost,
// VGPR=32 killed MLP). Keep split kernels, maximize loads-in-flight.

#define NIMG 16
#define HDIM 256
#define WDIM 256
#define CH   32
#define HW   (HDIM * WDIM)
#define BPI  64    // sum-kernel blocks per image

typedef float f32x4 __attribute__((ext_vector_type(4)));

// ---------------------------------------------------------------------------
// Kernel 1: per-(n,c) partial sums. 1024 blocks, 4 independent acc chains.
// partials layout: [BPI][NIMG][CH]
// ---------------------------------------------------------------------------
__global__ __launch_bounds__(256) void st_sum_kernel(
    const float* __restrict__ x, float* __restrict__ partials) {
    const int n   = blockIdx.x >> 6;
    const int blk = blockIdx.x & (BPI - 1);
    const int tid = threadIdx.x;
    const int cg  = tid & 7;    // float4 channel group
    const int sp  = tid >> 3;   // spatial slot 0..31

    const float4* xp = (const float4*)(x + (size_t)n * HW * CH);
    float4 a0 = make_float4(0.f, 0.f, 0.f, 0.f);
    float4 a1 = make_float4(0.f, 0.f, 0.f, 0.f);
    float4 a2 = make_float4(0.f, 0.f, 0.f, 0.f);
    float4 a3 = make_float4(0.f, 0.f, 0.f, 0.f);
    // 32 spatial iterations, 4 independent chains of 8
    int s = blk * 32 + sp;   // stride between slots: BPI*32 = 2048
    #pragma unroll
    for (int it = 0; it < 8; ++it) {
        float4 v0 = xp[(size_t)(s       ) * 8 + cg];
        float4 v1 = xp[(size_t)(s + 2048) * 8 + cg];
        float4 v2 = xp[(size_t)(s + 4096) * 8 + cg];
        float4 v3 = xp[(size_t)(s + 6144) * 8 + cg];
        a0.x += v0.x; a0.y += v0.y; a0.z += v0.z; a0.w += v0.w;
        a1.x += v1.x; a1.y += v1.y; a1.z += v1.z; a1.w += v1.w;
        a2.x += v2.x; a2.y += v2.y; a2.z += v2.z; a2.w += v2.w;
        a3.x += v3.x; a3.y += v3.y; a3.z += v3.z; a3.w += v3.w;
        s += 8192;
    }
    a0.x += a1.x; a0.y += a1.y; a0.z += a1.z; a0.w += a1.w;
    a2.x += a3.x; a2.y += a3.y; a2.z += a3.z; a2.w += a3.w;
    a0.x += a2.x; a0.y += a2.y; a0.z += a2.z; a0.w += a2.w;

    __shared__ float4 red[256];
    red[tid] = a0;
    __syncthreads();
    for (int stride = 16; stride >= 1; stride >>= 1) {
        if (sp < stride) {
            float4 o = red[(sp + stride) * 8 + cg];
            a0.x += o.x; a0.y += o.y; a0.z += o.z; a0.w += o.w;
            red[tid] = a0;
        }
        __syncthreads();
    }
    if (sp == 0) {
        ((float4*)(partials + ((size_t)blk * NIMG + n) * CH))[cg] = a0;
    }
}

// ---------------------------------------------------------------------------
// Kernel 2: per-block theta recompute + bilinear gather.
// One block = 4x16 pixel tile, 2 px per thread, 8 corner loads in flight.
// 16384 blocks; XCD swizzle gives each XCD 2048 consecutive blocks = 2 images.
// ---------------------------------------------------------------------------
__global__ __launch_bounds__(256) void st_interp_kernel(
    const float* __restrict__ x, const float* __restrict__ partials,
    const float* __restrict__ W_loc, const float* __restrict__ b_loc,
    float* __restrict__ out) {
    const int bid = (int)blockIdx.x;
    const int swz = (bid & 7) * 2048 + (bid >> 3);  // 8 XCDs contiguous
    const int n   = swz >> 10;                      // 1024 blocks per image
    const int r   = swz & 1023;
    const int tid = threadIdx.x;

    // ---- theta from partials (identical in every block of image n) ----
    __shared__ float red2[8][CH];
    __shared__ float th_s[8];
    {
        const int c = tid & 31, g = tid >> 5;  // g = 0..7
        float s = 0.f;
        #pragma unroll
        for (int j = 0; j < 8; ++j)
            s += partials[(size_t)((g * 8 + j) * NIMG + n) * CH + c];
        red2[g][c] = s;
        __syncthreads();
        if (g == 0) {
            float m = 0.f;
            #pragma unroll
            for (int j = 0; j < 8; ++j) m += red2[j][c];
            red2[0][c] = m * (1.0f / (float)HW);  // mean
        }
        __syncthreads();
        if (tid < 6) {
            float acc = b_loc[tid];
            for (int c2 = 0; c2 < CH; ++c2)
                acc = fmaf(red2[0][c2], W_loc[c2 * 6 + tid], acc);
            th_s[tid] = acc;
        }
        __syncthreads();
    }
    const float t00 = th_s[0], t01 = th_s[1], t02 = th_s[2];
    const float t10 = th_s[3], t11 = th_s[4], t12 = th_s[5];

    // ---- gather: 4x16 tile, 2 pixels per thread ----
    const int ty = r >> 4;                         // 64 tile-rows (4 px)
    const int tx = r & 15;                         // 16 tile-cols (16 px)
    const int p  = tid >> 3;                       // pixel slot 0..31
    const int cg = tid & 7;                        // float4 channel group

    const int ho  = ty * 4 + (p >> 3);
    const int wo0 = tx * 16 + (p & 7);
    const int wo1 = wo0 + 8;

    const float gy  = fmaf((float)ho,  2.0f / 255.0f, -1.0f);
    const float gx0 = fmaf((float)wo0, 2.0f / 255.0f, -1.0f);
    const float gx1 = fmaf((float)wo1, 2.0f / 255.0f, -1.0f);

    const float uyA = (fmaf(t00, gy, fmaf(t01, gx0, t02)) + 1.0f) * 127.5f;
    const float uxA = (fmaf(t10, gy, fmaf(t11, gx0, t12)) + 1.0f) * 127.5f;
    const float uyB = (fmaf(t00, gy, fmaf(t01, gx1, t02)) + 1.0f) * 127.5f;
    const float uxB = (fmaf(t10, gy, fmaf(t11, gx1, t12)) + 1.0f) * 127.5f;

    const float fyA = floorf(uyA), fxA = floorf(uxA);
    const float fyB = floorf(uyB), fxB = floorf(uxB);
    const float ryA = uyA - fyA, rxA = uxA - fxA;
    const float ryB = uyB - fyB, rxB = uxB - fxB;

    const int iyA0 = min(max((int)fyA,     0), HDIM - 1);
    const int iyA1 = min(max((int)fyA + 1, 0), HDIM - 1);
    const int ixA0 = min(max((int)fxA,     0), WDIM - 1);
    const int ixA1 = min(max((int)fxA + 1, 0), WDIM - 1);
    const int iyB0 = min(max((int)fyB,     0), HDIM - 1);
    const int iyB1 = min(max((int)fyB + 1, 0), HDIM - 1);
    const int ixB0 = min(max((int)fxB,     0), WDIM - 1);
    const int ixB1 = min(max((int)fxB + 1, 0), WDIM - 1);

    const float4* xp = (const float4*)(x + (size_t)n * HW * CH);
    // issue all 8 loads before any consumption
    float4 a00 = xp[(size_t)(iyA0 * WDIM + ixA0) * 8 + cg];
    float4 a01 = xp[(size_t)(iyA0 * WDIM + ixA1) * 8 + cg];
    float4 a10 = xp[(size_t)(iyA1 * WDIM + ixA0) * 8 + cg];
    float4 a11 = xp[(size_t)(iyA1 * WDIM + ixA1) * 8 + cg];
    float4 b00 = xp[(size_t)(iyB0 * WDIM + ixB0) * 8 + cg];
    float4 b01 = xp[(size_t)(iyB0 * WDIM + ixB1) * 8 + cg];
    float4 b10 = xp[(size_t)(iyB1 * WDIM + ixB0) * 8 + cg];
    float4 b11 = xp[(size_t)(iyB1 * WDIM + ixB1) * 8 + cg];

    const float wA00 = (1.0f - ryA) * (1.0f - rxA);
    const float wA01 = (1.0f - ryA) * rxA;
    const float wA10 = ryA * (1.0f - rxA);
    const float wA11 = ryA * rxA;
    const float wB00 = (1.0f - ryB) * (1.0f - rxB);
    const float wB01 = (1.0f - ryB) * rxB;
    const float wB10 = ryB * (1.0f - rxB);
    const float wB11 = ryB * rxB;

    f32x4 oA, oB;
    oA.x = a00.x * wA00 + a01.x * wA01 + a10.x * wA10 + a11.x * wA11;
    oA.y = a00.y * wA00 + a01.y * wA01 + a10.y * wA10 + a11.y * wA11;
    oA.z = a00.z * wA00 + a01.z * wA01 + a10.z * wA10 + a11.z * wA11;
    oA.w = a00.w * wA00 + a01.w * wA01 + a10.w * wA10 + a11.w * wA11;
    oB.x = b00.x * wB00 + b01.x * wB01 + b10.x * wB10 + b11.x * wB11;
    oB.y = b00.y * wB00 + b01.y * wB01 + b10.y * wB10 + b11.y * wB11;
    oB.z = b00.z * wB00 + b01.z * wB01 + b10.z * wB10 + b11.z * wB11;
    oB.w = b00.w * wB00 + b01.w * wB01 + b10.w * wB10 + b11.w * wB11;

    f32x4* op = (f32x4*)(out + (size_t)n * HW * CH);
    __builtin_nontemporal_store(oA, &op[(size_t)(ho * WDIM + wo0) * 8 + cg]);
    __builtin_nontemporal_store(oB, &op[(size_t)(ho * WDIM + wo1) * 8 + cg]);
}

extern "C" void kernel_launch(void* const* d_in, const int* in_sizes, int n_in,
                              void* d_out, int out_size, void* d_ws, size_t ws_size,
                              hipStream_t stream) {
    const float* x     = (const float*)d_in[0];
    const float* W_loc = (const float*)d_in[1];
    const float* b_loc = (const float*)d_in[2];
    float* out = (float*)d_out;

    // workspace layout: partials[BPI*NIMG*CH] f32
    float* partials = (float*)d_ws;

    st_sum_kernel<<<NIMG * BPI, 256, 0, stream>>>(x, partials);
    st_interp_kernel<<<NIMG * (HW / 64), 256, 0, stream>>>(
        x, partials, W_loc, b_loc, out);
}

// Round 6
// 62.955 us; speedup vs baseline: 5.7281x; 1.0330x over previous
//
#include <hip/hip_runtime.h>

// Problem: SpatialTransform
//   x:     (16, 256, 256, 32) f32
//   W_loc: (32, 6) f32
//   b_loc: (6) f32
//   out:   (16, 256, 256, 32) f32
//
// out = bilinear_sample(x, affine_grid(theta)), theta = mean_pool(x) @ W_loc + b_loc
//
// Structure (R6): two kernels.
//   k1: per-(n,c) partial sums -> partials[BPI][NIMG][CH]   (HBM-read floor)
//   k2: per-block theta recompute (L2-hot partials), then bilinear gather with
//       4 px/thread and all 16 corner loads in flight (latency-bound phase).
// R3 lesson: cooperative fusion regressed 5x. R4/R5 lesson: gather is
// latency-bound (2px/thread bought 7us); push MLP further.

#define NIMG 16
#define HDIM 256
#define WDIM 256
#define CH   32
#define HW   (HDIM * WDIM)
#define BPI  64    // sum-kernel blocks per image

typedef float f32x4 __attribute__((ext_vector_type(4)));

// ---------------------------------------------------------------------------
// Kernel 1: per-(n,c) partial sums. 1024 blocks, 4 independent acc chains.
// partials layout: [BPI][NIMG][CH]
// ---------------------------------------------------------------------------
__global__ __launch_bounds__(256) void st_sum_kernel(
    const float* __restrict__ x, float* __restrict__ partials) {
    const int n   = blockIdx.x >> 6;
    const int blk = blockIdx.x & (BPI - 1);
    const int tid = threadIdx.x;
    const int cg  = tid & 7;    // float4 channel group
    const int sp  = tid >> 3;   // spatial slot 0..31

    const float4* xp = (const float4*)(x + (size_t)n * HW * CH);
    float4 a0 = make_float4(0.f, 0.f, 0.f, 0.f);
    float4 a1 = make_float4(0.f, 0.f, 0.f, 0.f);
    float4 a2 = make_float4(0.f, 0.f, 0.f, 0.f);
    float4 a3 = make_float4(0.f, 0.f, 0.f, 0.f);
    int s = blk * 32 + sp;   // slot stride: BPI*32 = 2048
    #pragma unroll
    for (int it = 0; it < 8; ++it) {
        float4 v0 = xp[(size_t)(s       ) * 8 + cg];
        float4 v1 = xp[(size_t)(s + 2048) * 8 + cg];
        float4 v2 = xp[(size_t)(s + 4096) * 8 + cg];
        float4 v3 = xp[(size_t)(s + 6144) * 8 + cg];
        a0.x += v0.x; a0.y += v0.y; a0.z += v0.z; a0.w += v0.w;
        a1.x += v1.x; a1.y += v1.y; a1.z += v1.z; a1.w += v1.w;
        a2.x += v2.x; a2.y += v2.y; a2.z += v2.z; a2.w += v2.w;
        a3.x += v3.x; a3.y += v3.y; a3.z += v3.z; a3.w += v3.w;
        s += 8192;
    }
    a0.x += a1.x; a0.y += a1.y; a0.z += a1.z; a0.w += a1.w;
    a2.x += a3.x; a2.y += a3.y; a2.z += a3.z; a2.w += a3.w;
    a0.x += a2.x; a0.y += a2.y; a0.z += a2.z; a0.w += a2.w;

    __shared__ float4 red[256];
    red[tid] = a0;
    __syncthreads();
    for (int stride = 16; stride >= 1; stride >>= 1) {
        if (sp < stride) {
            float4 o = red[(sp + stride) * 8 + cg];
            a0.x += o.x; a0.y += o.y; a0.z += o.z; a0.w += o.w;
            red[tid] = a0;
        }
        __syncthreads();
    }
    if (sp == 0) {
        ((float4*)(partials + ((size_t)blk * NIMG + n) * CH))[cg] = a0;
    }
}

// ---------------------------------------------------------------------------
// Kernel 2: per-block theta recompute + bilinear gather.
// One block = 4x32 pixel tile, 4 px per thread, 16 corner loads in flight.
// 8192 blocks; XCD swizzle gives each XCD 1024 consecutive blocks = 2 images.
// ---------------------------------------------------------------------------
__global__ __launch_bounds__(256) void st_interp_kernel(
    const float* __restrict__ x, const float* __restrict__ partials,
    const float* __restrict__ W_loc, const float* __restrict__ b_loc,
    float* __restrict__ out) {
    const int bid = (int)blockIdx.x;
    const int swz = (bid & 7) * 1024 + (bid >> 3);  // 8 XCDs contiguous
    const int n   = swz >> 9;                       // 512 blocks per image
    const int r   = swz & 511;
    const int tid = threadIdx.x;

    // ---- theta from partials (identical in every block of image n) ----
    __shared__ float red2[8][CH];
    __shared__ float th_s[8];
    {
        const int c = tid & 31, g = tid >> 5;  // g = 0..7
        float s = 0.f;
        #pragma unroll
        for (int j = 0; j < 8; ++j)
            s += partials[(size_t)((g * 8 + j) * NIMG + n) * CH + c];
        red2[g][c] = s;
        __syncthreads();
        if (g == 0) {
            float m = 0.f;
            #pragma unroll
            for (int j = 0; j < 8; ++j) m += red2[j][c];
            red2[0][c] = m * (1.0f / (float)HW);  // mean
        }
        __syncthreads();
        if (tid < 6) {
            float acc = b_loc[tid];
            for (int c2 = 0; c2 < CH; ++c2)
                acc = fmaf(red2[0][c2], W_loc[c2 * 6 + tid], acc);
            th_s[tid] = acc;
        }
        __syncthreads();
    }
    const float t00 = th_s[0], t01 = th_s[1], t02 = th_s[2];
    const float t10 = th_s[3], t11 = th_s[4], t12 = th_s[5];

    // ---- gather: 4x32 tile, 4 pixels per thread, 16 loads in flight ----
    const int ty = r >> 3;                         // 64 tile-rows (4 px each)
    const int tx = r & 7;                          // 8 tile-cols (32 px each)
    const int p  = tid >> 3;                       // pixel slot 0..31
    const int cg = tid & 7;                        // float4 channel group

    const int ho = ty * 4 + (p >> 3);
    const float gy = fmaf((float)ho, 2.0f / 255.0f, -1.0f);
    const float cy = fmaf(t00, gy, t02);           // uy before gx term
    const float cx = fmaf(t10, gy, t12);

    const float4* xp = (const float4*)(x + (size_t)n * HW * CH);

    int   off0[4], off1[4], off2[4], off3[4];
    float w00[4], w01[4], w10[4], w11[4];
    int   wo[4];
    #pragma unroll
    for (int k = 0; k < 4; ++k) {
        wo[k] = tx * 32 + (p & 7) + k * 8;
        const float gx = fmaf((float)wo[k], 2.0f / 255.0f, -1.0f);
        const float uy = (fmaf(t01, gx, cy) + 1.0f) * 127.5f;
        const float ux = (fmaf(t11, gx, cx) + 1.0f) * 127.5f;
        const float fy = floorf(uy), fx = floorf(ux);
        const float ry = uy - fy, rx = ux - fx;
        const int iy0 = min(max((int)fy,     0), HDIM - 1);
        const int iy1 = min(max((int)fy + 1, 0), HDIM - 1);
        const int ix0 = min(max((int)fx,     0), WDIM - 1);
        const int ix1 = min(max((int)fx + 1, 0), WDIM - 1);
        off0[k] = (iy0 * WDIM + ix0) * 8;
        off1[k] = (iy0 * WDIM + ix1) * 8;
        off2[k] = (iy1 * WDIM + ix0) * 8;
        off3[k] = (iy1 * WDIM + ix1) * 8;
        w00[k] = (1.0f - ry) * (1.0f - rx);
        w01[k] = (1.0f - ry) * rx;
        w10[k] = ry * (1.0f - rx);
        w11[k] = ry * rx;
    }

    // issue all 16 loads before any consumption
    float4 v00[4], v01[4], v10[4], v11[4];
    #pragma unroll
    for (int k = 0; k < 4; ++k) {
        v00[k] = xp[(size_t)off0[k] + cg];
        v01[k] = xp[(size_t)off1[k] + cg];
        v10[k] = xp[(size_t)off2[k] + cg];
        v11[k] = xp[(size_t)off3[k] + cg];
    }

    f32x4* op = (f32x4*)(out + (size_t)n * HW * CH);
    #pragma unroll
    for (int k = 0; k < 4; ++k) {
        f32x4 o;
        o.x = v00[k].x * w00[k] + v01[k].x * w01[k] + v10[k].x * w10[k] + v11[k].x * w11[k];
        o.y = v00[k].y * w00[k] + v01[k].y * w01[k] + v10[k].y * w10[k] + v11[k].y * w11[k];
        o.z = v00[k].z * w00[k] + v01[k].z * w01[k] + v10[k].z * w10[k] + v11[k].z * w11[k];
        o.w = v00[k].w * w00[k] + v01[k].w * w01[k] + v10[k].w * w10[k] + v11[k].w * w11[k];
        __builtin_nontemporal_store(o, &op[(size_t)(ho * WDIM + wo[k]) * 8 + cg]);
    }
}

extern "C" void kernel_launch(void* const* d_in, const int* in_sizes, int n_in,
                              void* d_out, int out_size, void* d_ws, size_t ws_size,
                              hipStream_t stream) {
    const float* x     = (const float*)d_in[0];
    const float* W_loc = (const float*)d_in[1];
    const float* b_loc = (const float*)d_in[2];
    float* out = (float*)d_out;

    // workspace layout: partials[BPI*NIMG*CH] f32
    float* partials = (float*)d_ws;

    st_sum_kernel<<<NIMG * BPI, 256, 0, stream>>>(x, partials);
    st_interp_kernel<<<NIMG * (HW / 128), 256, 0, stream>>>(
        x, partials, W_loc, b_loc, out);
}